// Round 5
// baseline (2200.035 us; speedup 1.0000x reference)
//
#include <hip/hip_runtime.h>
#include <hip/hip_bf16.h>
#include <hip/hip_cooperative_groups.h>

namespace cg = cooperative_groups;

// GCN via CSR counting-sort, CSR built in ONE cooperative kernel with all
// atomics XCD-local (L2-side) and ALL-INT (round-4 lesson: float atomics at
// workgroup scope lower to a CAS loop -> 300MB of memory-side RMW traffic).
//   phase1: cntdeg8[x][d] += (1<<32 | fix16(w))   (one native int64 atomic/edge)
//   phase2: dinv = rsqrt(1+deg), row_start scan, per-XCD cursor init
//   phase3: sorted[pos] = (src, dinv[s]*w*dinv[d]) (native int cursor atomics)
// Same workgroup = same XCD across phases => per-XCD sub-buckets exact.
// Then: t = x@W1 -> agg1 (fused self+bias+relu) = h1
//       -> agg2 fused with @W2+b2+log_softmax -> out.

#define D_IN 512
#define D_HID 16
#define D_OUT 64
#define BT 256
#define WSCALE 65536.0f

__device__ __forceinline__ int xcc_id() {
    int id;
    asm volatile("s_getreg_b32 %0, hwreg(HW_REG_XCC_ID)" : "=s"(id));
    return id & 7;
}

__global__ __launch_bounds__(BT) void csr_build_kernel(
        const int* __restrict__ src, const int* __restrict__ dst,
        const float* __restrict__ w,
        unsigned long long* __restrict__ cntdeg8, int* __restrict__ cursor8,
        int* __restrict__ row_start, float* __restrict__ dinv,
        int* __restrict__ bsum, float2* __restrict__ sorted,
        int N, int E) {
    cg::grid_group grid = cg::this_grid();
    const int x = xcc_id();
    const int tid = threadIdx.x;
    const int gtid = blockIdx.x * BT + tid;
    const int gsz = gridDim.x * BT;

    // ---- phase 1: per-XCD packed histogram (count | fixed-point wdeg) ----
    for (int e = gtid; e < E; e += gsz) {
        int d = dst[e];
        unsigned long long pk = ((unsigned long long)1 << 32) |
                                (unsigned long long)(unsigned)__float2uint_rn(w[e] * WSCALE);
        __hip_atomic_fetch_add(&cntdeg8[(size_t)x * N + d], pk,
                               __ATOMIC_RELAXED, __HIP_MEMORY_SCOPE_WORKGROUP);
    }
    __threadfence();  // release: write back XCD L2
    grid.sync();
    __threadfence();  // acquire: invalidate stale lines

    // ---- phase 2a: per-node totals, dinv, block-local scan ----
    __shared__ int ex[BT];
    __shared__ int tot_s[BT];
    const int chunk = (N + gridDim.x - 1) / gridDim.x;
    const int n = blockIdx.x * chunk + tid;
    int tot = 0;
    if (tid < chunk && n < N) {
        unsigned long long s = 0;
#pragma unroll
        for (int xx = 0; xx < 8; ++xx) s += cntdeg8[(size_t)xx * N + n];
        tot = (int)(s >> 32);
        float dg = (float)(unsigned)(s & 0xffffffffULL) * (1.0f / WSCALE);
        dinv[n] = __frsqrt_rn(1.0f + dg);
    }
    tot_s[tid] = tot;
    ex[tid] = tot;
    __syncthreads();
    for (int off = 1; off < BT; off <<= 1) {
        int v = (tid >= off) ? ex[tid - off] : 0;
        __syncthreads();
        ex[tid] += v;
        __syncthreads();
    }
    if (tid == BT - 1) bsum[blockIdx.x] = ex[BT - 1];
    __threadfence();
    grid.sync();
    __threadfence();

    // ---- phase 2b: global base, row_start, per-XCD cursor init ----
    int part = 0;
    for (int i = tid; i < (int)blockIdx.x; i += BT) part += bsum[i];
#pragma unroll
    for (int off = 32; off; off >>= 1) part += __shfl_down(part, off, 64);
    __shared__ int wred[BT / 64];
    if ((tid & 63) == 0) wred[tid >> 6] = part;
    __syncthreads();
    int bbase = 0;
#pragma unroll
    for (int i = 0; i < BT / 64; ++i) bbase += wred[i];

    if (tid < chunk && n < N) {
        int rs = bbase + ex[tid] - tot_s[tid];  // exclusive scan value
        row_start[n] = rs;
        int c = rs;
#pragma unroll
        for (int xx = 0; xx < 8; ++xx) {
            cursor8[(size_t)xx * N + n] = c;
            c += (int)(cntdeg8[(size_t)xx * N + n] >> 32);
        }
    }
    if (gtid == 0) row_start[N] = E;
    __threadfence();
    grid.sync();
    __threadfence();

    // ---- phase 3: scatter (same workgroup => same XCD as phase 1) ----
    for (int e = gtid; e < E; e += gsz) {
        int s = src[e], d = dst[e];
        float nm = dinv[s] * w[e] * dinv[d];
        int pos = __hip_atomic_fetch_add(&cursor8[(size_t)x * N + d], 1,
                                         __ATOMIC_RELAXED, __HIP_MEMORY_SCOPE_WORKGROUP);
        sorted[pos] = make_float2(__int_as_float(s), nm);
    }
}

// t[N][16] = x[N][512] @ W1[512][16]; 16 lanes/row, each owns 8 float4 k-slices.
__global__ __launch_bounds__(256) void gemm1_kernel(const float* __restrict__ x,
                                                    const float* __restrict__ W1,
                                                    float* __restrict__ t, int N) {
    __shared__ float w1t[16 * 520];
    for (int idx = threadIdx.x; idx < D_IN * D_HID; idx += 256) {
        int k = idx >> 4, j = idx & 15;
        w1t[j * 520 + k] = W1[idx];
    }
    __syncthreads();

    const int wave = threadIdx.x >> 6;
    const int lane = threadIdx.x & 63;
    const int g = lane >> 4;
    const int s = lane & 15;

    int row = blockIdx.x * 16 + wave * 4 + g;
    if (row < N) {
        const float4* xr = (const float4*)(x + (size_t)row * D_IN);
        float4 xv[8];
#pragma unroll
        for (int i = 0; i < 8; ++i) xv[i] = xr[s + 16 * i];
        float acc[16];
#pragma unroll
        for (int j = 0; j < 16; ++j) acc[j] = 0.0f;
#pragma unroll
        for (int i = 0; i < 8; ++i) {
            int kb = 4 * s + 64 * i;
#pragma unroll
            for (int j = 0; j < 16; ++j) {
                const float4 wv = *(const float4*)&w1t[j * 520 + kb];
                acc[j] += xv[i].x * wv.x + xv[i].y * wv.y + xv[i].z * wv.z + xv[i].w * wv.w;
            }
        }
#pragma unroll
        for (int j = 0; j < 16; ++j) {
#pragma unroll
            for (int m = 1; m < 16; m <<= 1) acc[j] += __shfl_xor(acc[j], m, 64);
        }
        float v = acc[0];
#pragma unroll
        for (int j = 1; j < 16; ++j) v = (s == j) ? acc[j] : v;
        t[(size_t)row * 16 + s] = v;
    }
}

// Layer-1 aggregation. One wave per node; lane = k*4+q: 16 edges in flight,
// each edge's 16-dim feature row read as 4 lanes x float4 (one 64B line).
// h1 = relu(edge_sum + dinv^2 * t + b1).  norm already baked into sorted.
__global__ __launch_bounds__(256) void agg1_kernel(const float2* __restrict__ sorted,
                                                   const int* __restrict__ row_start,
                                                   const float* __restrict__ feat,
                                                   const float* __restrict__ dinv,
                                                   const float* __restrict__ b1,
                                                   float* __restrict__ outp, int N) {
    int node = blockIdx.x * 4 + (threadIdx.x >> 6);
    if (node >= N) return;
    const int lane = threadIdx.x & 63;
    const int q = lane & 3, k = lane >> 2;
    const int beg = row_start[node], end = row_start[node + 1];
    float4 acc = make_float4(0.f, 0.f, 0.f, 0.f);
    for (int e = beg + k; e < end; e += 16) {
        float2 p = sorted[e];
        int s = __float_as_int(p.x);
        const float4 f = *(const float4*)(feat + (size_t)s * 16 + q * 4);
        acc.x += p.y * f.x; acc.y += p.y * f.y; acc.z += p.y * f.z; acc.w += p.y * f.w;
    }
#pragma unroll
    for (int m = 4; m < 64; m <<= 1) {
        acc.x += __shfl_xor(acc.x, m, 64);
        acc.y += __shfl_xor(acc.y, m, 64);
        acc.z += __shfl_xor(acc.z, m, 64);
        acc.w += __shfl_xor(acc.w, m, 64);
    }
    float dn = dinv[node];
    float dn2 = dn * dn;
    if (k == 0) {
        const float4 sv = *(const float4*)(feat + (size_t)node * 16 + q * 4);
        const float4 bb = *(const float4*)(b1 + q * 4);
        float4 r;
        r.x = fmaxf(acc.x + dn2 * sv.x + bb.x, 0.0f);
        r.y = fmaxf(acc.y + dn2 * sv.y + bb.y, 0.0f);
        r.z = fmaxf(acc.z + dn2 * sv.z + bb.z, 0.0f);
        r.w = fmaxf(acc.w + dn2 * sv.w + bb.w, 0.0f);
        *(float4*)(outp + (size_t)node * 16 + q * 4) = r;
    }
}

// Layer-2 aggregation fused with @W2 + b2 + log_softmax.
__global__ __launch_bounds__(256) void agg2out_kernel(const float2* __restrict__ sorted,
                                                      const int* __restrict__ row_start,
                                                      const float* __restrict__ h1,
                                                      const float* __restrict__ dinv,
                                                      const float* __restrict__ W2,
                                                      const float* __restrict__ b2,
                                                      float* __restrict__ out, int N) {
    __shared__ float w2s[16 * 64];
    __shared__ float b2s[64];
    for (int idx = threadIdx.x; idx < 16 * 64; idx += 256) w2s[idx] = W2[idx];
    if (threadIdx.x < 64) b2s[threadIdx.x] = b2[threadIdx.x];
    __syncthreads();

    int node = blockIdx.x * 4 + (threadIdx.x >> 6);
    if (node >= N) return;
    const int lane = threadIdx.x & 63;
    const int q = lane & 3, k = lane >> 2;
    const int beg = row_start[node], end = row_start[node + 1];
    float4 acc = make_float4(0.f, 0.f, 0.f, 0.f);
    for (int e = beg + k; e < end; e += 16) {
        float2 p = sorted[e];
        int s = __float_as_int(p.x);
        const float4 f = *(const float4*)(h1 + (size_t)s * 16 + q * 4);
        acc.x += p.y * f.x; acc.y += p.y * f.y; acc.z += p.y * f.z; acc.w += p.y * f.w;
    }
#pragma unroll
    for (int m = 4; m < 64; m <<= 1) {
        acc.x += __shfl_xor(acc.x, m, 64);
        acc.y += __shfl_xor(acc.y, m, 64);
        acc.z += __shfl_xor(acc.z, m, 64);
        acc.w += __shfl_xor(acc.w, m, 64);
    }
    float dn = dinv[node];
    float dn2 = dn * dn;
    const float4 hv = *(const float4*)(h1 + (size_t)node * 16 + q * 4);
    float vc[4];
    vc[0] = acc.x + dn2 * hv.x;
    vc[1] = acc.y + dn2 * hv.y;
    vc[2] = acc.z + dn2 * hv.z;
    vc[3] = acc.w + dn2 * hv.w;

    float z = b2s[lane];
#pragma unroll
    for (int j = 0; j < 16; ++j) {
        float vj = __shfl(vc[j & 3], j >> 2, 64);  // source lane k=0, q=j>>2
        z += vj * w2s[j * 64 + lane];
    }
    float m = z;
#pragma unroll
    for (int off = 32; off; off >>= 1) m = fmaxf(m, __shfl_xor(m, off, 64));
    float ez = __expf(z - m);
    float ssum = ez;
#pragma unroll
    for (int off = 32; off; off >>= 1) ssum += __shfl_xor(ssum, off, 64);
    out[(size_t)node * 64 + lane] = z - m - __logf(ssum);
}

extern "C" void kernel_launch(void* const* d_in, const int* in_sizes, int n_in,
                              void* d_out, int out_size, void* d_ws, size_t ws_size,
                              hipStream_t stream) {
    const float* x  = (const float*)d_in[0];
    const int*   ei = (const int*)d_in[1];
    const float* ew = (const float*)d_in[2];
    const float* W1 = (const float*)d_in[3];
    const float* b1 = (const float*)d_in[4];
    const float* W2 = (const float*)d_in[5];
    const float* b2 = (const float*)d_in[6];
    float* out = (float*)d_out;

    int N = in_sizes[0] / D_IN;
    int E = in_sizes[2];
    const int* srcI = ei;
    const int* dstI = ei + E;

    // ws layout (float units):
    //   [0, 16N)           : cntdeg8[8N x u64]      -- reused as t[16N] after build
    //   [16N, 24N)         : cursor8[8N x int]      -- dead after build; overlaid by h1
    //   [16N, 32N)         : h1[16N]                (written after cursor8 is dead)
    //   [32N, 33N+2)       : row_start[N+1]
    //   [33N+2, 34N+2)     : dinv[N]
    //   [34N+2, +2048)     : bsum
    //   [34N+2050, +2E)    : sorted (float2 per edge)
    float* ws = (float*)d_ws;
    unsigned long long* cntdeg8 = (unsigned long long*)ws;
    float*  t         = ws;
    int*    cursor8   = (int*)(ws + 16 * (size_t)N);
    float*  h1        = ws + 16 * (size_t)N;
    int*    row_start = (int*)(ws + 32 * (size_t)N);
    float*  dinv      = ws + 33 * (size_t)N + 2;
    int*    bsum      = (int*)(ws + 34 * (size_t)N + 2);
    float2* sorted    = (float2*)(ws + 34 * (size_t)N + 2050);

    hipMemsetAsync(cntdeg8, 0, (size_t)8 * N * sizeof(unsigned long long), stream);

    // Cooperative grid: as many co-resident blocks as the device allows (cap 2048).
    int gblk = 1024;
    int bpm = 0, ncu = 0;
    if (hipOccupancyMaxActiveBlocksPerMultiprocessor(&bpm, (const void*)csr_build_kernel,
                                                     BT, 0) == hipSuccess &&
        hipDeviceGetAttribute(&ncu, hipDeviceAttributeMultiprocessorCount, 0) == hipSuccess &&
        bpm > 0 && ncu > 0) {
        int cap = bpm * ncu;
        gblk = cap < 2048 ? cap : 2048;
        if (gblk < 512) gblk = 512;  // keep chunk <= BT in phase 2
    }

    void* args[] = {(void*)&srcI, (void*)&dstI, (void*)&ew, (void*)&cntdeg8, (void*)&cursor8,
                    (void*)&row_start, (void*)&dinv, (void*)&bsum, (void*)&sorted,
                    (void*)&N, (void*)&E};
    if (hipLaunchCooperativeKernel((const void*)csr_build_kernel, dim3(gblk), dim3(BT),
                                   args, 0, stream) != hipSuccess) {
        hipLaunchCooperativeKernel((const void*)csr_build_kernel, dim3(1024), dim3(BT),
                                   args, 0, stream);
    }

    gemm1_kernel<<<(N + 15) / 16, 256, 0, stream>>>(x, W1, t, N);

    agg1_kernel<<<(N + 3) / 4, 256, 0, stream>>>(sorted, row_start, t, dinv, b1, h1, N);
    agg2out_kernel<<<(N + 3) / 4, 256, 0, stream>>>(sorted, row_start, h1, dinv, W2, b2, out, N);
}

// Round 6
// 1073.042 us; speedup vs baseline: 2.0503x; 2.0503x over previous
//
#include <hip/hip_runtime.h>
#include <hip/hip_bf16.h>

// GCN, fully atomic-free on global memory.
// Rounds 1-5 lesson: scattered global atomics on MI355X execute memory-side
// (~20 Gops/s, ~32B HBM traffic each) regardless of scope qualifier; at
// E=3.2M every per-edge global atomic costs >=160us. This version bins edges
// by dst-bucket (64 nodes) with dense scans for exact placement, then
// aggregates per-bucket in LDS with ds_add_f32 (ucode-fast) only.
//
// Pipeline:
//   A1 histA:   per-(block,bucket) counts via LDS histogram -> offpart
//   A2 scanRow: exclusive scan over blocks per bucket; bucket totals
//      scanBase: exclusive scan over buckets -> base
//   A3 scatterA: exact-position scatter of (src|localdst, w), LDS cursors
//   degB:    per-bucket LDS accumulate of w -> dinv = rsqrt(1+deg)
//   gemm1s:  tS = dinv .* (x @ W1)          (factor dinv[src] out of agg)
//   D1:      per-bucket LDS msg += w*tS[src]; h1S = dinv*relu(dinv*(msg+tS)+b1)
//   D2:      same with h1S; fused @W2+b2+log_softmax epilogue

#define D_IN 512
#define D_HID 16
#define D_OUT 64
#define BUCK_BITS 6
#define BUCK 64
#define MAXB 1600      // max buckets (N <= 102400)
#define NBLKA 512      // binning chunk blocks
#define ABT 256

// ---- A1: per-chunk histogram over dst buckets ----
__global__ __launch_bounds__(ABT) void histA_kernel(const int* __restrict__ dst,
        unsigned* __restrict__ offpart, int E, int chunk, int nbuck) {
    __shared__ unsigned h[MAXB];
    for (int i = threadIdx.x; i < nbuck; i += ABT) h[i] = 0;
    __syncthreads();
    const int k = blockIdx.x;
    const int beg = k * chunk, end = min(beg + chunk, E);
    for (int e = beg + threadIdx.x; e < end; e += ABT)
        atomicAdd(&h[dst[e] >> BUCK_BITS], 1u);
    __syncthreads();
    for (int b = threadIdx.x; b < nbuck; b += ABT)
        offpart[(size_t)b * NBLKA + k] = h[b];
}

// ---- A2a: per-bucket exclusive scan over the NBLKA partials ----
__global__ __launch_bounds__(NBLKA) void scanRow_kernel(unsigned* __restrict__ offpart,
        unsigned* __restrict__ total) {
    __shared__ unsigned s[NBLKA];
    const int b = blockIdx.x, t = threadIdx.x;
    unsigned v = offpart[(size_t)b * NBLKA + t];
    const unsigned orig = v;
    s[t] = v;
    __syncthreads();
    for (int off = 1; off < NBLKA; off <<= 1) {
        unsigned u = (t >= off) ? s[t - off] : 0;
        __syncthreads();
        s[t] += u;
        __syncthreads();
    }
    offpart[(size_t)b * NBLKA + t] = s[t] - orig;   // exclusive
    if (t == NBLKA - 1) total[b] = s[t];
}

// ---- A2b: bucket base = exclusive scan of totals ----
__global__ __launch_bounds__(256) void scanBase_kernel(const unsigned* __restrict__ total,
        unsigned* __restrict__ base, int nbuck, int E) {
    __shared__ unsigned ex[256];
    const int t = threadIdx.x;
    const int per = (nbuck + 255) / 256;
    const int beg = min(t * per, nbuck), end = min(beg + per, nbuck);
    unsigned s = 0;
    for (int i = beg; i < end; ++i) s += total[i];
    const unsigned orig = s;
    ex[t] = s;
    __syncthreads();
    for (int off = 1; off < 256; off <<= 1) {
        unsigned u = (t >= off) ? ex[t - off] : 0;
        __syncthreads();
        ex[t] += u;
        __syncthreads();
    }
    unsigned run = ex[t] - orig;
    for (int i = beg; i < end; ++i) { base[i] = run; run += total[i]; }
    if (t == 0) base[nbuck] = (unsigned)E;
}

// ---- A3: exact-position scatter; cursors live in LDS ----
__global__ __launch_bounds__(ABT) void scatterA_kernel(const int* __restrict__ src,
        const int* __restrict__ dst, const float* __restrict__ w,
        const unsigned* __restrict__ offpart, const unsigned* __restrict__ base,
        uint2* __restrict__ binned, int E, int chunk, int nbuck) {
    __shared__ unsigned rc[MAXB];
    const int k = blockIdx.x;
    for (int b = threadIdx.x; b < nbuck; b += ABT)
        rc[b] = base[b] + offpart[(size_t)b * NBLKA + k];
    __syncthreads();
    const int beg = k * chunk, end = min(beg + chunk, E);
    for (int e = beg + threadIdx.x; e < end; e += ABT) {
        const int d = dst[e];
        const int b = d >> BUCK_BITS;
        const unsigned pos = atomicAdd(&rc[b], 1u);   // LDS atomic
        uint2 pk;
        pk.x = (unsigned)src[e] | ((unsigned)(d & (BUCK - 1)) << 17);
        pk.y = __float_as_uint(w[e]);
        binned[pos] = pk;
    }
}

// ---- degB: dinv = rsqrt(1 + sum w) per node, via per-bucket LDS ----
__global__ __launch_bounds__(256) void degB_kernel(const uint2* __restrict__ binned,
        const unsigned* __restrict__ base, float* __restrict__ dinv, int N) {
    __shared__ float dg[BUCK];
    if (threadIdx.x < BUCK) dg[threadIdx.x] = 0.0f;
    __syncthreads();
    const int b = blockIdx.x;
    const unsigned beg = base[b], end = base[b + 1];
    for (unsigned e = beg + threadIdx.x; e < end; e += 256) {
        const uint2 p = binned[e];
        atomicAdd(&dg[p.x >> 17], __uint_as_float(p.y));
    }
    __syncthreads();
    if (threadIdx.x < BUCK) {
        const int n = b * BUCK + threadIdx.x;
        if (n < N) dinv[n] = __frsqrt_rn(1.0f + dg[threadIdx.x]);
    }
}

// ---- gemm1s: tS[N][16] = dinv .* (x[N][512] @ W1[512][16]) ----
__global__ __launch_bounds__(256) void gemm1s_kernel(const float* __restrict__ x,
        const float* __restrict__ W1, const float* __restrict__ dinv,
        float* __restrict__ tS, int N) {
    __shared__ float w1t[16 * 520];
    for (int idx = threadIdx.x; idx < D_IN * D_HID; idx += 256) {
        int k = idx >> 4, j = idx & 15;
        w1t[j * 520 + k] = W1[idx];
    }
    __syncthreads();

    const int wave = threadIdx.x >> 6;
    const int lane = threadIdx.x & 63;
    const int g = lane >> 4;
    const int s = lane & 15;

    const int row = blockIdx.x * 16 + wave * 4 + g;
    if (row < N) {
        const float4* xr = (const float4*)(x + (size_t)row * D_IN);
        float4 xv[8];
#pragma unroll
        for (int i = 0; i < 8; ++i) xv[i] = xr[s + 16 * i];
        float acc[16];
#pragma unroll
        for (int j = 0; j < 16; ++j) acc[j] = 0.0f;
#pragma unroll
        for (int i = 0; i < 8; ++i) {
            int kb = 4 * s + 64 * i;
#pragma unroll
            for (int j = 0; j < 16; ++j) {
                const float4 wv = *(const float4*)&w1t[j * 520 + kb];
                acc[j] += xv[i].x * wv.x + xv[i].y * wv.y + xv[i].z * wv.z + xv[i].w * wv.w;
            }
        }
#pragma unroll
        for (int j = 0; j < 16; ++j) {
#pragma unroll
            for (int m = 1; m < 16; m <<= 1) acc[j] += __shfl_xor(acc[j], m, 64);
        }
        float v = acc[0];
#pragma unroll
        for (int j = 1; j < 16; ++j) v = (s == j) ? acc[j] : v;
        tS[(size_t)row * 16 + s] = v * dinv[row];
    }
}

// Shared accumulation: 4 lanes/edge (q = lane&3 owns 4 dims), unroll x2.
// Wave's 16 edge reads are contiguous (e = beg+g) -> one 128B transaction.
__device__ __forceinline__ void accum_bucket(const uint2* __restrict__ binned,
        unsigned beg, unsigned end, const float* __restrict__ feat,
        float* msg, int g, int q) {
    unsigned e = beg + g;
    for (; e + 64 < end; e += 128) {
        const uint2 p0 = binned[e];
        const uint2 p1 = binned[e + 64];
        const float w0 = __uint_as_float(p0.y);
        const float w1 = __uint_as_float(p1.y);
        const float4 f0 = *(const float4*)(feat + (size_t)(p0.x & 0x1FFFFu) * 16 + q * 4);
        const float4 f1 = *(const float4*)(feat + (size_t)(p1.x & 0x1FFFFu) * 16 + q * 4);
        float* m0 = &msg[(p0.x >> 17) * 17 + q * 4];
        float* m1 = &msg[(p1.x >> 17) * 17 + q * 4];
        atomicAdd(m0 + 0, w0 * f0.x); atomicAdd(m0 + 1, w0 * f0.y);
        atomicAdd(m0 + 2, w0 * f0.z); atomicAdd(m0 + 3, w0 * f0.w);
        atomicAdd(m1 + 0, w1 * f1.x); atomicAdd(m1 + 1, w1 * f1.y);
        atomicAdd(m1 + 2, w1 * f1.z); atomicAdd(m1 + 3, w1 * f1.w);
    }
    if (e < end) {
        const uint2 p = binned[e];
        const float wv = __uint_as_float(p.y);
        const float4 f = *(const float4*)(feat + (size_t)(p.x & 0x1FFFFu) * 16 + q * 4);
        float* m = &msg[(p.x >> 17) * 17 + q * 4];
        atomicAdd(m + 0, wv * f.x); atomicAdd(m + 1, wv * f.y);
        atomicAdd(m + 2, wv * f.z); atomicAdd(m + 3, wv * f.w);
    }
}

// ---- D1: layer-1 aggregate; h1S = dinv * relu(dinv*(msg + tS) + b1) ----
__global__ __launch_bounds__(256) void aggD1_kernel(const uint2* __restrict__ binned,
        const unsigned* __restrict__ base, const float* __restrict__ tS,
        const float* __restrict__ dinv, const float* __restrict__ b1,
        float* __restrict__ h1S, int N) {
    __shared__ float msg[BUCK * 17];
    for (int i = threadIdx.x; i < BUCK * 17; i += 256) msg[i] = 0.0f;
    __syncthreads();
    const int b = blockIdx.x;
    accum_bucket(binned, base[b], base[b + 1], tS, msg, threadIdx.x >> 2, threadIdx.x & 3);
    __syncthreads();
    for (int idx = threadIdx.x; idx < BUCK * 16; idx += 256) {
        const int nl = idx >> 4, j = idx & 15;
        const int n = b * BUCK + nl;
        if (n < N) {
            const float dn = dinv[n];
            const float v = dn * (msg[nl * 17 + j] + tS[(size_t)n * 16 + j]);
            const float h = fmaxf(v + b1[j], 0.0f);
            h1S[(size_t)n * 16 + j] = dn * h;
        }
    }
}

// ---- D2: layer-2 aggregate fused with @W2 + b2 + log_softmax ----
__global__ __launch_bounds__(256) void aggD2_kernel(const uint2* __restrict__ binned,
        const unsigned* __restrict__ base, const float* __restrict__ h1S,
        const float* __restrict__ dinv, const float* __restrict__ W2,
        const float* __restrict__ b2, float* __restrict__ out, int N) {
    __shared__ float msg[BUCK * 17];
    __shared__ float w2s[16 * 64];
    __shared__ float b2s[64];
    for (int i = threadIdx.x; i < 16 * 64; i += 256) w2s[i] = W2[i];
    if (threadIdx.x < 64) b2s[threadIdx.x] = b2[threadIdx.x];
    for (int i = threadIdx.x; i < BUCK * 17; i += 256) msg[i] = 0.0f;
    __syncthreads();
    const int b = blockIdx.x;
    accum_bucket(binned, base[b], base[b + 1], h1S, msg, threadIdx.x >> 2, threadIdx.x & 3);
    __syncthreads();
    // v2 = dinv*(msg + h1S_self), in place in LDS
    for (int idx = threadIdx.x; idx < BUCK * 16; idx += 256) {
        const int nl = idx >> 4, j = idx & 15;
        const int n = b * BUCK + nl;
        if (n < N)
            msg[nl * 17 + j] = dinv[n] * (msg[nl * 17 + j] + h1S[(size_t)n * 16 + j]);
    }
    __syncthreads();
    // wave w handles 16 nodes; lane = output channel
    const int wv = threadIdx.x >> 6, lane = threadIdx.x & 63;
    for (int nl = wv * (BUCK / 4); nl < (wv + 1) * (BUCK / 4); ++nl) {
        const int n = b * BUCK + nl;
        if (n >= N) break;
        float z = b2s[lane];
#pragma unroll
        for (int j = 0; j < 16; ++j) z += msg[nl * 17 + j] * w2s[j * 64 + lane];
        float m = z;
#pragma unroll
        for (int off = 32; off; off >>= 1) m = fmaxf(m, __shfl_xor(m, off, 64));
        float ssum = __expf(z - m);
#pragma unroll
        for (int off = 32; off; off >>= 1) ssum += __shfl_xor(ssum, off, 64);
        out[(size_t)n * 64 + lane] = z - m - __logf(ssum);
    }
}

extern "C" void kernel_launch(void* const* d_in, const int* in_sizes, int n_in,
                              void* d_out, int out_size, void* d_ws, size_t ws_size,
                              hipStream_t stream) {
    const float* x  = (const float*)d_in[0];
    const int*   ei = (const int*)d_in[1];
    const float* ew = (const float*)d_in[2];
    const float* W1 = (const float*)d_in[3];
    const float* b1 = (const float*)d_in[4];
    const float* W2 = (const float*)d_in[5];
    const float* b2 = (const float*)d_in[6];
    float* out = (float*)d_out;

    const int N = in_sizes[0] / D_IN;
    const int E = in_sizes[2];
    const int* srcI = ei;
    const int* dstI = ei + E;

    const int nbuck = (N + BUCK - 1) >> BUCK_BITS;     // 1563 @ N=100000
    const int npad  = nbuck * BUCK;
    const int chunkA = (E + NBLKA - 1) / NBLKA;

    // ws layout (4B units):
    //   [0, 2E)                 binned (uint2 per edge)
    //   [2E, 2E+16*npad)        tS   (offpart[nbuck*NBLKA] overlaid; dead pre-gemm1)
    //   [2E+16n, 2E+32n)        h1S
    //   [2E+32n, 2E+33n)        dinv
    //   then base[nbuck+1], total[nbuck]
    float* ws = (float*)d_ws;
    uint2*    binned  = (uint2*)ws;
    float*    tS      = ws + 2 * (size_t)E;
    unsigned* offpart = (unsigned*)tS;                 // dead before gemm1s
    float*    h1S     = ws + 2 * (size_t)E + 16 * (size_t)npad;
    float*    dinv    = ws + 2 * (size_t)E + 32 * (size_t)npad;
    unsigned* baseB   = (unsigned*)(ws + 2 * (size_t)E + 33 * (size_t)npad);
    unsigned* totalB  = baseB + nbuck + 1;

    histA_kernel<<<NBLKA, ABT, 0, stream>>>(dstI, offpart, E, chunkA, nbuck);
    scanRow_kernel<<<nbuck, NBLKA, 0, stream>>>(offpart, totalB);
    scanBase_kernel<<<1, 256, 0, stream>>>(totalB, baseB, nbuck, E);
    scatterA_kernel<<<NBLKA, ABT, 0, stream>>>(srcI, dstI, ew, offpart, baseB,
                                               binned, E, chunkA, nbuck);
    degB_kernel<<<nbuck, 256, 0, stream>>>(binned, baseB, dinv, N);
    gemm1s_kernel<<<(N + 15) / 16, 256, 0, stream>>>(x, W1, dinv, tS, N);
    aggD1_kernel<<<nbuck, 256, 0, stream>>>(binned, baseB, tS, dinv, b1, h1S, N);
    aggD2_kernel<<<nbuck, 256, 0, stream>>>(binned, baseB, h1S, dinv, W2, b2, out, N);
}